// Round 1
// baseline (518.345 us; speedup 1.0000x reference)
//
#include <hip/hip_runtime.h>
#include <math.h>

#define H_IMG 64
#define W_IMG 64
#define PIX   (H_IMG * W_IMG)   // 4096
#define NB    4
#define NHEADS 8
#define HD    32
#define CDIM  256
#define QKV_C 768
#define ATT_SCALE 0.17677669529663687f  // 32^-0.5

// ----------------------------------------------------------------------------
// fp32 GEMM with bias: Y[b] = W (MxK) @ X[b] (KxN) + bias
// 128x128 tile, 256 threads, 8x8 per thread, KT=16. All dims divide evenly
// for our shapes (M in {768,256}, K=256, N=4096).
// ----------------------------------------------------------------------------
__launch_bounds__(256)
__global__ void gemm_bias_f32(const float* __restrict__ W,
                              const float* __restrict__ bias,
                              const float* __restrict__ X,
                              float* __restrict__ Y,
                              int M, int K, int N) {
    __shared__ float As[16][128];   // As[k][m]
    __shared__ float Bs[16][128];   // Bs[k][n]

    const int b = blockIdx.z;
    const float* Xb = X + (size_t)b * K * N;
    float* Yb = Y + (size_t)b * M * N;

    const int m0 = blockIdx.y * 128;
    const int n0 = blockIdx.x * 128;
    const int t  = threadIdx.x;
    const int tx = t & 15;          // 0..15
    const int ty = t >> 4;          // 0..15
    const int m_base = ty * 8;
    const int n_base = tx * 8;

    float acc[8][8];
#pragma unroll
    for (int i = 0; i < 8; i++)
#pragma unroll
        for (int j = 0; j < 8; j++) acc[i][j] = 0.f;

    for (int c0 = 0; c0 < K; c0 += 16) {
        // Load A chunk: 128 rows x 16 cols = 512 float4, 2 per thread (transposed store)
#pragma unroll
        for (int i = 0; i < 2; i++) {
            int idx = t + i * 256;           // 0..511
            int mm = idx >> 2;               // 0..127
            int k4 = idx & 3;                // 0..3
            float4 v = *(const float4*)(W + (size_t)(m0 + mm) * K + c0 + k4 * 4);
            As[k4 * 4 + 0][mm] = v.x;
            As[k4 * 4 + 1][mm] = v.y;
            As[k4 * 4 + 2][mm] = v.z;
            As[k4 * 4 + 3][mm] = v.w;
        }
        // Load B chunk: 16 rows x 128 cols = 512 float4, 2 per thread
#pragma unroll
        for (int i = 0; i < 2; i++) {
            int idx = t + i * 256;           // 0..511
            int kk = idx >> 5;               // 0..15
            int n4 = idx & 31;               // 0..31
            float4 v = *(const float4*)(Xb + (size_t)(c0 + kk) * N + n0 + n4 * 4);
            *(float4*)&Bs[kk][n4 * 4] = v;
        }
        __syncthreads();

#pragma unroll
        for (int kk = 0; kk < 16; kk++) {
            float a[8], bb[8];
            *(float4*)&a[0]  = *(const float4*)&As[kk][m_base];
            *(float4*)&a[4]  = *(const float4*)&As[kk][m_base + 4];
            *(float4*)&bb[0] = *(const float4*)&Bs[kk][n_base];
            *(float4*)&bb[4] = *(const float4*)&Bs[kk][n_base + 4];
#pragma unroll
            for (int mi = 0; mi < 8; mi++)
#pragma unroll
                for (int ni = 0; ni < 8; ni++)
                    acc[mi][ni] += a[mi] * bb[ni];
        }
        __syncthreads();
    }

    // Epilogue: add bias, store float4
#pragma unroll
    for (int mi = 0; mi < 8; mi++) {
        int row = m0 + m_base + mi;
        float bs = bias[row];
        float* yp = Yb + (size_t)row * N + n0 + n_base;
#pragma unroll
        for (int j4 = 0; j4 < 2; j4++) {
            float4 v;
            v.x = acc[mi][j4 * 4 + 0] + bs;
            v.y = acc[mi][j4 * 4 + 1] + bs;
            v.z = acc[mi][j4 * 4 + 2] + bs;
            v.w = acc[mi][j4 * 4 + 3] + bs;
            *(float4*)(yp + j4 * 4) = v;
        }
    }
}

// ----------------------------------------------------------------------------
// Local neighborhood attention, one range (kernel size KS, dilation DIL).
// Thread = one pixel of one (batch, head). Block (64,4): lane = x coordinate
// so all k/v/q global accesses are coalesced along pixels.
// Zero-padding semantics: OOB neighbors contribute logit=rpb[l] to the
// softmax denominator with zero value (matches jnp.pad in reference).
// Logits are O(0.1) here so max-free exp-sum softmax is numerically safe.
// ----------------------------------------------------------------------------
template <int KS, int DIL>
__launch_bounds__(256)
__global__ void attn_range(const float* __restrict__ qkv,
                           const float* __restrict__ rpb,
                           float* __restrict__ out,
                           int h0, int nh) {
    const int bh = blockIdx.x;
    const int b  = bh / nh;
    const int hl = bh % nh;       // head index within this range
    const int h  = h0 + hl;
    const int px = threadIdx.x;                       // 0..63
    const int py = blockIdx.y * 4 + threadIdx.y;      // 0..63
    const int p  = py * W_IMG + px;

    const float* qp = qkv + ((size_t)b * QKV_C + h * HD) * PIX + p;
    const float* kp = qkv + ((size_t)b * QKV_C + CDIM + h * HD) * PIX;
    const float* vp = qkv + ((size_t)b * QKV_C + 2 * CDIM + h * HD) * PIX;
    const float* rp = rpb + hl * KS * KS;

    float q[HD];
#pragma unroll
    for (int d = 0; d < HD; d++) q[d] = qp[(size_t)d * PIX] * ATT_SCALE;

    float denom = 0.f;
    float acc[HD];
#pragma unroll
    for (int d = 0; d < HD; d++) acc[d] = 0.f;

#pragma unroll 1
    for (int i = 0; i < KS; i++) {
        const int yy = py + (i - KS / 2) * DIL;
        const bool yin = (unsigned)yy < (unsigned)H_IMG;
#pragma unroll
        for (int j = 0; j < KS; j++) {
            const int xx = px + (j - KS / 2) * DIL;
            float s = rp[i * KS + j];
            const bool inb = yin && ((unsigned)xx < (unsigned)W_IMG);
            if (inb) {
                const int p2 = yy * W_IMG + xx;
                const float* kpp = kp + p2;
                float d0 = 0.f, d1 = 0.f, d2 = 0.f, d3 = 0.f;
#pragma unroll
                for (int d = 0; d < HD; d += 4) {
                    d0 += q[d + 0] * kpp[(size_t)(d + 0) * PIX];
                    d1 += q[d + 1] * kpp[(size_t)(d + 1) * PIX];
                    d2 += q[d + 2] * kpp[(size_t)(d + 2) * PIX];
                    d3 += q[d + 3] * kpp[(size_t)(d + 3) * PIX];
                }
                s += (d0 + d1) + (d2 + d3);
                const float wgt = __expf(s);
                denom += wgt;
                const float* vpp = vp + p2;
#pragma unroll
                for (int d = 0; d < HD; d++)
                    acc[d] += wgt * vpp[(size_t)d * PIX];
            } else {
                denom += __expf(s);   // zero-padded neighbor: logit = rpb, v = 0
            }
        }
    }

    const float inv = 1.f / denom;
    float* op = out + ((size_t)b * CDIM + h * HD) * PIX + p;
#pragma unroll
    for (int d = 0; d < HD; d++) op[(size_t)d * PIX] = acc[d] * inv;
}

// ----------------------------------------------------------------------------
extern "C" void kernel_launch(void* const* d_in, const int* in_sizes, int n_in,
                              void* d_out, int out_size, void* d_ws, size_t ws_size,
                              hipStream_t stream) {
    const float* x      = (const float*)d_in[0];
    const float* qkv_w  = (const float*)d_in[1];
    const float* qkv_b  = (const float*)d_in[2];
    const float* proj_w = (const float*)d_in[3];
    const float* proj_b = (const float*)d_in[4];
    const float* rpb0   = (const float*)d_in[5];
    const float* rpb1   = (const float*)d_in[6];
    const float* rpb2   = (const float*)d_in[7];
    float* out = (float*)d_out;

    // workspace: qkv (4*768*4096 fp32 = 48 MB) | att (4*256*4096 fp32 = 16 MB)
    float* qkv = (float*)d_ws;
    float* att = qkv + (size_t)NB * QKV_C * PIX;

    dim3 gblk(256);
    // QKV projection: M=768, K=256, N=4096, per batch
    gemm_bias_f32<<<dim3(PIX / 128, QKV_C / 128, NB), gblk, 0, stream>>>(
        qkv_w, qkv_b, x, qkv, QKV_C, CDIM, PIX);

    dim3 ablk(64, 4);
    attn_range<5, 1><<<dim3(NB * 4, 16), ablk, 0, stream>>>(qkv, rpb0, att, 0, 4);
    attn_range<7, 2><<<dim3(NB * 3, 16), ablk, 0, stream>>>(qkv, rpb1, att, 4, 3);
    attn_range<9, 3><<<dim3(NB * 1, 16), ablk, 0, stream>>>(qkv, rpb2, att, 7, 1);

    // Output projection: M=256, K=256, N=4096, per batch
    gemm_bias_f32<<<dim3(PIX / 128, CDIM / 128, NB), gblk, 0, stream>>>(
        proj_w, proj_b, att, out, CDIM, CDIM, PIX);
}

// Round 2
// 455.456 us; speedup vs baseline: 1.1381x; 1.1381x over previous
//
#include <hip/hip_runtime.h>
#include <math.h>

#define H_IMG 64
#define W_IMG 64
#define PIX   (H_IMG * W_IMG)   // 4096
#define NB    4
#define NHEADS 8
#define HD    32
#define CDIM  256
#define QKV_C 768
#define ATT_SCALE 0.17677669529663687f  // 32^-0.5

// ----------------------------------------------------------------------------
// fp32 GEMM with bias: Y[b] = W (MxK) @ X[b] (KxN) + bias
// 128x128 tile, 256 threads, 8x8 per thread, KT=16.
// ----------------------------------------------------------------------------
__launch_bounds__(256)
__global__ void gemm_bias_f32(const float* __restrict__ W,
                              const float* __restrict__ bias,
                              const float* __restrict__ X,
                              float* __restrict__ Y,
                              int M, int K, int N) {
    __shared__ float As[16][128];   // As[k][m]
    __shared__ float Bs[16][128];   // Bs[k][n]

    const int b = blockIdx.z;
    const float* Xb = X + (size_t)b * K * N;
    float* Yb = Y + (size_t)b * M * N;

    const int m0 = blockIdx.y * 128;
    const int n0 = blockIdx.x * 128;
    const int t  = threadIdx.x;
    const int tx = t & 15;          // 0..15
    const int ty = t >> 4;          // 0..15
    const int m_base = ty * 8;
    const int n_base = tx * 8;

    float acc[8][8];
#pragma unroll
    for (int i = 0; i < 8; i++)
#pragma unroll
        for (int j = 0; j < 8; j++) acc[i][j] = 0.f;

    for (int c0 = 0; c0 < K; c0 += 16) {
#pragma unroll
        for (int i = 0; i < 2; i++) {
            int idx = t + i * 256;           // 0..511
            int mm = idx >> 2;               // 0..127
            int k4 = idx & 3;                // 0..3
            float4 v = *(const float4*)(W + (size_t)(m0 + mm) * K + c0 + k4 * 4);
            As[k4 * 4 + 0][mm] = v.x;
            As[k4 * 4 + 1][mm] = v.y;
            As[k4 * 4 + 2][mm] = v.z;
            As[k4 * 4 + 3][mm] = v.w;
        }
#pragma unroll
        for (int i = 0; i < 2; i++) {
            int idx = t + i * 256;           // 0..511
            int kk = idx >> 5;               // 0..15
            int n4 = idx & 31;               // 0..31
            float4 v = *(const float4*)(Xb + (size_t)(c0 + kk) * N + n0 + n4 * 4);
            *(float4*)&Bs[kk][n4 * 4] = v;
        }
        __syncthreads();

#pragma unroll
        for (int kk = 0; kk < 16; kk++) {
            float a[8], bb[8];
            *(float4*)&a[0]  = *(const float4*)&As[kk][m_base];
            *(float4*)&a[4]  = *(const float4*)&As[kk][m_base + 4];
            *(float4*)&bb[0] = *(const float4*)&Bs[kk][n_base];
            *(float4*)&bb[4] = *(const float4*)&Bs[kk][n_base + 4];
#pragma unroll
            for (int mi = 0; mi < 8; mi++)
#pragma unroll
                for (int ni = 0; ni < 8; ni++)
                    acc[mi][ni] += a[mi] * bb[ni];
        }
        __syncthreads();
    }

#pragma unroll
    for (int mi = 0; mi < 8; mi++) {
        int row = m0 + m_base + mi;
        float bs = bias[row];
        float* yp = Yb + (size_t)row * N + n0 + n_base;
#pragma unroll
        for (int j4 = 0; j4 < 2; j4++) {
            float4 v;
            v.x = acc[mi][j4 * 4 + 0] + bs;
            v.y = acc[mi][j4 * 4 + 1] + bs;
            v.z = acc[mi][j4 * 4 + 2] + bs;
            v.w = acc[mi][j4 * 4 + 3] + bs;
            *(float4*)(yp + j4 * 4) = v;
        }
    }
}

// ----------------------------------------------------------------------------
// Fused local neighborhood attention, ALL ranges in one launch.
// Grid: (NB*NHEADS, 16 y-tiles), block (64,4) — 512 blocks, 8 waves/CU.
// Per-block head index selects (KS, DIL) wave-uniformly: no divergence.
// Zero-padding semantics: OOB neighbors contribute logit=rpb[l] to the
// softmax denominator with zero value (matches jnp.pad in reference).
// Logits are O(0.1) so max-free exp-sum softmax is numerically safe in fp32.
// ----------------------------------------------------------------------------
template <int KS, int DIL>
__device__ __forceinline__ void attn_px(const float* __restrict__ qkv,
                                        const float* __restrict__ rp,
                                        float* __restrict__ out,
                                        int b, int h, int px, int py) {
    const int p = py * W_IMG + px;

    const float* qp = qkv + ((size_t)b * QKV_C + h * HD) * PIX + p;
    const float* kp = qkv + ((size_t)b * QKV_C + CDIM + h * HD) * PIX;
    const float* vp = qkv + ((size_t)b * QKV_C + 2 * CDIM + h * HD) * PIX;

    float q[HD];
#pragma unroll
    for (int d = 0; d < HD; d++) q[d] = qp[(size_t)d * PIX] * ATT_SCALE;

    float denom = 0.f;
    float acc[HD];
#pragma unroll
    for (int d = 0; d < HD; d++) acc[d] = 0.f;

#pragma unroll 1
    for (int i = 0; i < KS; i++) {
        const int yy = py + (i - KS / 2) * DIL;
        const bool yin = (unsigned)yy < (unsigned)H_IMG;
#pragma unroll
        for (int j = 0; j < KS; j++) {
            const int xx = px + (j - KS / 2) * DIL;
            float s = rp[i * KS + j];
            const bool inb = yin && ((unsigned)xx < (unsigned)W_IMG);
            if (inb) {
                const int p2 = yy * W_IMG + xx;
                const float* kpp = kp + p2;
                float d0 = 0.f, d1 = 0.f, d2 = 0.f, d3 = 0.f;
#pragma unroll
                for (int d = 0; d < HD; d += 4) {
                    d0 += q[d + 0] * kpp[(size_t)(d + 0) * PIX];
                    d1 += q[d + 1] * kpp[(size_t)(d + 1) * PIX];
                    d2 += q[d + 2] * kpp[(size_t)(d + 2) * PIX];
                    d3 += q[d + 3] * kpp[(size_t)(d + 3) * PIX];
                }
                s += (d0 + d1) + (d2 + d3);
                const float wgt = __expf(s);
                denom += wgt;
                const float* vpp = vp + p2;
#pragma unroll
                for (int d = 0; d < HD; d++)
                    acc[d] += wgt * vpp[(size_t)d * PIX];
            } else {
                denom += __expf(s);   // zero-padded neighbor: logit = rpb, v = 0
            }
        }
    }

    const float inv = 1.f / denom;
    float* op = out + ((size_t)b * CDIM + h * HD) * PIX + p;
#pragma unroll
    for (int d = 0; d < HD; d++) op[(size_t)d * PIX] = acc[d] * inv;
}

__launch_bounds__(256)
__global__ void attn_fused(const float* __restrict__ qkv,
                           const float* __restrict__ rpb0,
                           const float* __restrict__ rpb1,
                           const float* __restrict__ rpb2,
                           float* __restrict__ out) {
    const int bh = blockIdx.x;
    const int b  = bh >> 3;
    const int h  = bh & 7;
    const int px = threadIdx.x;                       // 0..63
    const int py = blockIdx.y * 4 + threadIdx.y;      // 0..63

    if (h < 4) {
        attn_px<5, 1>(qkv, rpb0 + h * 25, out, b, h, px, py);
    } else if (h < 7) {
        attn_px<7, 2>(qkv, rpb1 + (h - 4) * 49, out, b, h, px, py);
    } else {
        attn_px<9, 3>(qkv, rpb2, out, b, h, px, py);
    }
}

// ----------------------------------------------------------------------------
extern "C" void kernel_launch(void* const* d_in, const int* in_sizes, int n_in,
                              void* d_out, int out_size, void* d_ws, size_t ws_size,
                              hipStream_t stream) {
    const float* x      = (const float*)d_in[0];
    const float* qkv_w  = (const float*)d_in[1];
    const float* qkv_b  = (const float*)d_in[2];
    const float* proj_w = (const float*)d_in[3];
    const float* proj_b = (const float*)d_in[4];
    const float* rpb0   = (const float*)d_in[5];
    const float* rpb1   = (const float*)d_in[6];
    const float* rpb2   = (const float*)d_in[7];
    float* out = (float*)d_out;

    // workspace: qkv (4*768*4096 fp32 = 48 MB) | att (4*256*4096 fp32 = 16 MB)
    float* qkv = (float*)d_ws;
    float* att = qkv + (size_t)NB * QKV_C * PIX;

    dim3 gblk(256);
    // QKV projection: M=768, K=256, N=4096, per batch
    gemm_bias_f32<<<dim3(PIX / 128, QKV_C / 128, NB), gblk, 0, stream>>>(
        qkv_w, qkv_b, x, qkv, QKV_C, CDIM, PIX);

    // Fused multi-range attention: 512 blocks, 4 waves each
    attn_fused<<<dim3(NB * NHEADS, 16), dim3(64, 4), 0, stream>>>(
        qkv, rpb0, rpb1, rpb2, att);

    // Output projection: M=256, K=256, N=4096, per batch
    gemm_bias_f32<<<dim3(PIX / 128, CDIM / 128, NB), gblk, 0, stream>>>(
        proj_w, proj_b, att, out, CDIM, CDIM, PIX);
}